// Round 1
// baseline (95.272 us; speedup 1.0000x reference)
//
#include <hip/hip_runtime.h>

#define HW_   12544   // 112*112
#define W_    112
#define C_    128
#define OHW_  3136    // 56*56
#define OW_   56

// Pass 1: per-batch, per-phase sum of squares of the raw input.
// grid = (98, 32): 98 chunks per batch sample, each block handles 4096 float4.
__global__ __launch_bounds__(256) void phase_norms(const float* __restrict__ inp,
                                                   float* __restrict__ sums) {
    const int b = blockIdx.y;
    const float4* src = (const float4*)(inp + (size_t)b * (C_ * HW_));
    const unsigned tid = threadIdx.x;
    const unsigned base = blockIdx.x * 4096u + tid;

    float s[4] = {0.f, 0.f, 0.f, 0.f};
#pragma unroll
    for (int k = 0; k < 16; ++k) {
        unsigned g = base + k * 256u;      // float4 index within the sample
        float4 v = src[g];
        unsigned hp = (g / 28u) & 1u;      // 28 float4 per row; 112 rows/plane (even)
        s[hp]      += v.x * v.x + v.z * v.z;   // w even -> phases 0/1
        s[hp + 2u] += v.y * v.y + v.w * v.w;   // w odd  -> phases 2/3
    }

    // wave (64-lane) reduce each bin
#pragma unroll
    for (int p = 0; p < 4; ++p) {
        float v = s[p];
        for (int off = 32; off > 0; off >>= 1) v += __shfl_down(v, off);
        s[p] = v;
    }

    __shared__ float bs[4];
    if (tid < 4) bs[tid] = 0.f;
    __syncthreads();
    if ((tid & 63u) == 0u) {
#pragma unroll
        for (int p = 0; p < 4; ++p) atomicAdd(&bs[p], s[p]);
    }
    __syncthreads();
    if (tid < 4) atomicAdd(&sums[b * 4 + tid], bs[tid]);
}

// Pass 2: one block per (b,c) plane. Stage plane in LDS, blur + select phase.
__global__ __launch_bounds__(256) void blur_select(const float* __restrict__ inp,
                                                   const float* __restrict__ sums,
                                                   float* __restrict__ out) {
    __shared__ float tile[HW_];
    const int bc = blockIdx.x;
    const int b  = bc >> 7;              // / C_
    const float4* src = (const float4*)(inp + (size_t)bc * HW_);
    float4* t4 = (float4*)tile;
    for (int i = threadIdx.x; i < HW_ / 4; i += 256) t4[i] = src[i];

    // inline argmax (strict '>' == first occurrence, matches jnp.argmax)
    const float n0 = sums[b * 4 + 0], n1 = sums[b * 4 + 1];
    const float n2 = sums[b * 4 + 2], n3 = sums[b * 4 + 3];
    int idx = 0; float best = n0;
    if (n1 > best) { best = n1; idx = 1; }
    if (n2 > best) { best = n2; idx = 2; }
    if (n3 > best) { best = n3; idx = 3; }
    const int dr = idx & 1, dc = idx >> 1;

    __syncthreads();

    float* o = out + (size_t)bc * OHW_;
    for (unsigned t = threadIdx.x; t < OHW_; t += 256) {
        const int oh = t / OW_;
        const int ow = t - oh * OW_;
        const int rb = oh * 2 + dr - 1;
        const int cb = ow * 2 + dc - 1;
        int r[4], c[4];
#pragma unroll
        for (int k = 0; k < 4; ++k) {
            int j  = rb + k;
            r[k] = (j  < 0 ? -j  : (j  > 111 ? 222 - j  : j)) * W_;
            int jc = cb + k;
            c[k] = (jc < 0 ? -jc : (jc > 111 ? 222 - jc : jc));
        }
        float acc = 0.f;
#pragma unroll
        for (int kh = 0; kh < 4; ++kh) {
            const float w = (kh == 1 || kh == 2) ? 3.f : 1.f;
            const float h = tile[r[kh] + c[0]] + 3.f * tile[r[kh] + c[1]]
                          + 3.f * tile[r[kh] + c[2]] + tile[r[kh] + c[3]];
            acc += w * h;
        }
        o[t] = acc * 0.015625f;   // /64
    }
}

extern "C" void kernel_launch(void* const* d_in, const int* in_sizes, int n_in,
                              void* d_out, int out_size, void* d_ws, size_t ws_size,
                              hipStream_t stream) {
    const float* inp = (const float*)d_in[0];
    float* sums = (float*)d_ws;
    hipMemsetAsync(d_ws, 0, 32 * 4 * sizeof(float), stream);
    phase_norms<<<dim3(98, 32), 256, 0, stream>>>(inp, sums);
    blur_select<<<4096, 256, 0, stream>>>(inp, sums, (float*)d_out);
}